// Round 2
// baseline (3215.431 us; speedup 1.0000x reference)
//
#include <hip/hip_runtime.h>

#define NV   50000
#define NR   5
#define NT   8
#define CIN  64
#define COUT 64
#define VPB  4      // vertices per block (one per wave)

// block = 256 threads = 4 waves; each wave owns one vertex.
// grid = NV / VPB = 12500 (exact, no tail).
__global__ __launch_bounds__(256) void geo_conv_kernel(
    const float* __restrict__ signal,    // [NV][CIN]
    const float* __restrict__ bary_w,    // [NV][NR][NT][3]
    const int*   __restrict__ bary_idx,  // [NV][NR][NT][3]
    const float* __restrict__ kern,      // [NR][NT][CIN][COUT]
    float*       __restrict__ out)       // [NV][COUT]
{
    // x stored as [vertex][i][c][j] so a (i,c) slice is 8 contiguous floats.
    __shared__ __align__(16) float xs[VPB][NR][CIN][NT];   // 40 KB
    __shared__ float wsh[VPB][NR * NT * 3];                // 1.92 KB
    __shared__ int   ish[VPB][NR * NT * 3];                // 1.92 KB

    const int tid   = threadIdx.x;
    const int wave  = tid >> 6;
    const int lane  = tid & 63;
    const int vbase = blockIdx.x * VPB;

    // ---- stage barycentric weights / indices into LDS (coalesced) ----
    for (int e = tid; e < VPB * NR * NT * 3; e += 256) {
        int s = e / (NR * NT * 3);
        int r = e - s * (NR * NT * 3);
        wsh[s][r] = bary_w[(vbase + s) * (NR * NT * 3) + r];
        ish[s][r] = bary_idx[(vbase + s) * (NR * NT * 3) + r];
    }
    __syncthreads();

    // ---- phase A: pullback x[i,j,c] = sum_t w_t * signal[idx_t, c] ----
    // wave s handles vertex slot s; lanes = channels (coalesced signal rows)
    {
        const int s = wave;
        for (int ij = 0; ij < NR * NT; ++ij) {
            const int i = ij >> 3;
            const int j = ij & 7;
            const float w0 = wsh[s][ij * 3 + 0];
            const float w1 = wsh[s][ij * 3 + 1];
            const float w2 = wsh[s][ij * 3 + 2];
            const int   i0 = ish[s][ij * 3 + 0];
            const int   i1 = ish[s][ij * 3 + 1];
            const int   i2 = ish[s][ij * 3 + 2];
            float xv = w0 * signal[i0 * CIN + lane]
                     + w1 * signal[i1 * CIN + lane]
                     + w2 * signal[i2 * CIN + lane];
            xs[s][i][lane][j] = xv;
        }
    }
    __syncthreads();

    // ---- phase B: conv[k,d] = sum_{i,m,c} x[i,(m-k)%8,c] * K[i,m,c,d] ----
    // fp64 accumulation: the argmax-over-rotations step is decided by norm
    // gaps that can be ~1e-4; fp32 accumulation error (~2e-4 on norm^2)
    // flips it at a handful of vertices -> absmax ~1.5. fp64 makes our
    // conv essentially exact relative to the fp32 reference's own noise.
    double acc[NT];
    #pragma unroll
    for (int k = 0; k < NT; ++k) acc[k] = 0.0;

    const int s = wave;
    const int d = lane;
    for (int i = 0; i < NR; ++i) {
        const float* __restrict__ Ki = kern + i * (NT * CIN * COUT);
        for (int c = 0; c < CIN; ++c) {
            // broadcast-read the 8 rotations of x for this (i,c)
            const float4 xa = *reinterpret_cast<const float4*>(&xs[s][i][c][0]);
            const float4 xb = *reinterpret_cast<const float4*>(&xs[s][i][c][4]);
            const double x8[NT] = {(double)xa.x, (double)xa.y, (double)xa.z, (double)xa.w,
                                   (double)xb.x, (double)xb.y, (double)xb.z, (double)xb.w};
            #pragma unroll
            for (int m = 0; m < NT; ++m) {
                const double kv = (double)Ki[(m * CIN + c) * COUT + d];  // coalesced over d
                #pragma unroll
                for (int k = 0; k < NT; ++k) {
                    acc[k] = fma(x8[(m - k + NT) & (NT - 1)], kv, acc[k]);
                }
            }
        }
    }

    // ---- phase C: squared norms per rotation, first-max argmax, relu ----
    double nk[NT];
    #pragma unroll
    for (int k = 0; k < NT; ++k) {
        double n = acc[k] * acc[k];
        #pragma unroll
        for (int off = 32; off >= 1; off >>= 1)
            n += __shfl_xor(n, off);
        nk[k] = n;
    }
    int best = 0;
    double bn = nk[0];
    #pragma unroll
    for (int k = 1; k < NT; ++k) {
        if (nk[k] > bn) { bn = nk[k]; best = k; }   // strict > keeps first max
    }
    double sel = acc[0];
    #pragma unroll
    for (int k = 1; k < NT; ++k) sel = (best == k) ? acc[k] : sel;
    float outv = (float)sel;
    outv = fmaxf(outv, 0.0f);
    out[(vbase + s) * COUT + d] = outv;
}

extern "C" void kernel_launch(void* const* d_in, const int* in_sizes, int n_in,
                              void* d_out, int out_size, void* d_ws, size_t ws_size,
                              hipStream_t stream) {
    const float* signal   = (const float*)d_in[0];
    const float* bary_w   = (const float*)d_in[1];
    const int*   bary_idx = (const int*)d_in[2];
    const float* kern     = (const float*)d_in[3];
    float* out = (float*)d_out;

    dim3 grid(NV / VPB);   // 12500
    dim3 block(256);
    geo_conv_kernel<<<grid, block, 0, stream>>>(signal, bary_w, bary_idx, kern, out);
}

// Round 3
// 2104.744 us; speedup vs baseline: 1.5277x; 1.5277x over previous
//
#include <hip/hip_runtime.h>

#define NV   50000
#define NR   5
#define NT   8
#define CIN  64
#define COUT 64
#define VPB  4              // vertices per block (one per wave)
#define BARY (NR*NT*3)      // 120

// ---------------- pass 1: fp32 compute, flag near-tie argmax ----------------
__global__ __launch_bounds__(256) void geo_conv_f32(
    const float* __restrict__ signal,    // [NV][CIN]
    const float* __restrict__ bary_w,    // [NV][NR][NT][3]
    const int*   __restrict__ bary_idx,  // [NV][NR][NT][3]
    const float* __restrict__ kern,      // [NR][NT][CIN][COUT]
    float*       __restrict__ out,       // [NV][COUT]
    int*         __restrict__ wl)        // wl[0]=count, wl[1..]=vertex ids
{
    __shared__ __align__(16) float xs[VPB][NR][CIN][NT];   // 40 KB
    __shared__ float wsh[VPB][BARY];
    __shared__ int   ish[VPB][BARY];

    const int tid   = threadIdx.x;
    const int wave  = tid >> 6;
    const int lane  = tid & 63;
    const int vbase = blockIdx.x * VPB;

    for (int e = tid; e < VPB * BARY; e += 256) {
        int s = e / BARY, r = e - s * BARY;
        wsh[s][r] = bary_w[(vbase + s) * BARY + r];
        ish[s][r] = bary_idx[(vbase + s) * BARY + r];
    }
    __syncthreads();

    {   // pullback: x[i,j,c] = sum_t w_t * signal[idx_t, c]; lanes = channels
        const int s = wave;
        for (int ij = 0; ij < NR * NT; ++ij) {
            int i = ij >> 3, j = ij & 7;
            float w0 = wsh[s][ij*3], w1 = wsh[s][ij*3+1], w2 = wsh[s][ij*3+2];
            int   i0 = ish[s][ij*3], i1 = ish[s][ij*3+1], i2 = ish[s][ij*3+2];
            xs[s][i][lane][j] = w0 * signal[i0*CIN + lane]
                              + w1 * signal[i1*CIN + lane]
                              + w2 * signal[i2*CIN + lane];
        }
    }
    __syncthreads();

    float acc[NT];
    #pragma unroll
    for (int k = 0; k < NT; ++k) acc[k] = 0.0f;

    const int s = wave, d = lane;
    for (int i = 0; i < NR; ++i) {
        const float* __restrict__ Ki = kern + i * (NT * CIN * COUT);
        for (int c = 0; c < CIN; ++c) {
            float4 xa = *reinterpret_cast<const float4*>(&xs[s][i][c][0]);
            float4 xb = *reinterpret_cast<const float4*>(&xs[s][i][c][4]);
            float x8[NT] = {xa.x, xa.y, xa.z, xa.w, xb.x, xb.y, xb.z, xb.w};
            #pragma unroll
            for (int m = 0; m < NT; ++m) {
                float kv = Ki[(m * CIN + c) * COUT + d];
                #pragma unroll
                for (int k = 0; k < NT; ++k)
                    acc[k] = fmaf(x8[(m - k + NT) & (NT - 1)], kv, acc[k]);
            }
        }
    }

    // rotation norms^2 in fp64 (from fp32 accs) so the gap test is trustworthy
    double nk[NT];
    #pragma unroll
    for (int k = 0; k < NT; ++k) {
        double n = (double)acc[k] * (double)acc[k];
        #pragma unroll
        for (int off = 32; off >= 1; off >>= 1) n += __shfl_xor(n, off);
        nk[k] = n;
    }
    int best = 0; double bn = nk[0], sec = -1.0e300;
    #pragma unroll
    for (int k = 1; k < NT; ++k) {
        if (nk[k] > bn)       { sec = bn; bn = nk[k]; best = k; }
        else if (nk[k] > sec) { sec = nk[k]; }
    }
    const int v = vbase + s;
    // fp32-vs-true norm^2 error ~3e-5; threshold gives ~200x safety margin.
    if (bn - sec <= 4.0e-3 + 3.0e-5 * bn) {
        if (lane == 0) { int pos = atomicAdd(wl, 1); wl[1 + pos] = v; }
    } else {
        float sel = acc[0];
        #pragma unroll
        for (int k = 1; k < NT; ++k) sel = (best == k) ? acc[k] : sel;
        out[v * COUT + d] = fmaxf(sel, 0.0f);
    }
}

// ---------- pass 2: exact fp64 recompute for flagged vertices ----------
// wl != nullptr: process wl[1..wl[0]]; wl == nullptr: process 0..nall-1.
__global__ __launch_bounds__(256) void geo_refine_f64(
    const float* __restrict__ signal,
    const float* __restrict__ bary_w,
    const int*   __restrict__ bary_idx,
    const float* __restrict__ kern,
    float*       __restrict__ out,
    const int*   __restrict__ wl,
    int nall)
{
    __shared__ __align__(16) float xs[4][NR][CIN][NT];   // per-wave slot, 40 KB
    const int wave = threadIdx.x >> 6;
    const int lane = threadIdx.x & 63;
    const int count = wl ? wl[0] : nall;
    const int nw = gridDim.x * 4;

    for (int w = blockIdx.x * 4 + wave; w < count; w += nw) {
        const int v = wl ? wl[1 + w] : w;

        // pullback (wave-local; no block barrier needed — one wave owns xs[wave])
        for (int ij = 0; ij < NR * NT; ++ij) {
            int i = ij >> 3, j = ij & 7;
            int base = v * BARY + ij * 3;
            float w0 = bary_w[base], w1 = bary_w[base+1], w2 = bary_w[base+2];
            int   i0 = bary_idx[base], i1 = bary_idx[base+1], i2 = bary_idx[base+2];
            xs[wave][i][lane][j] = w0 * signal[i0*CIN + lane]
                                 + w1 * signal[i1*CIN + lane]
                                 + w2 * signal[i2*CIN + lane];
        }

        double acc[NT];
        #pragma unroll
        for (int k = 0; k < NT; ++k) acc[k] = 0.0;
        for (int i = 0; i < NR; ++i) {
            const float* __restrict__ Ki = kern + i * (NT * CIN * COUT);
            for (int c = 0; c < CIN; ++c) {
                float4 xa = *reinterpret_cast<const float4*>(&xs[wave][i][c][0]);
                float4 xb = *reinterpret_cast<const float4*>(&xs[wave][i][c][4]);
                double x8[NT] = {(double)xa.x, (double)xa.y, (double)xa.z, (double)xa.w,
                                 (double)xb.x, (double)xb.y, (double)xb.z, (double)xb.w};
                #pragma unroll
                for (int m = 0; m < NT; ++m) {
                    double kv = (double)Ki[(m * CIN + c) * COUT + lane];
                    #pragma unroll
                    for (int k = 0; k < NT; ++k)
                        acc[k] = fma(x8[(m - k + NT) & (NT - 1)], kv, acc[k]);
                }
            }
        }

        double nk[NT];
        #pragma unroll
        for (int k = 0; k < NT; ++k) {
            double n = acc[k] * acc[k];
            #pragma unroll
            for (int off = 32; off >= 1; off >>= 1) n += __shfl_xor(n, off);
            nk[k] = n;
        }
        int best = 0; double bn = nk[0];
        #pragma unroll
        for (int k = 1; k < NT; ++k)
            if (nk[k] > bn) { bn = nk[k]; best = k; }
        double sel = acc[0];
        #pragma unroll
        for (int k = 1; k < NT; ++k) sel = (best == k) ? acc[k] : sel;
        out[v * COUT + lane] = fmaxf((float)sel, 0.0f);
    }
}

extern "C" void kernel_launch(void* const* d_in, const int* in_sizes, int n_in,
                              void* d_out, int out_size, void* d_ws, size_t ws_size,
                              hipStream_t stream) {
    const float* signal   = (const float*)d_in[0];
    const float* bary_w   = (const float*)d_in[1];
    const int*   bary_idx = (const int*)d_in[2];
    const float* kern     = (const float*)d_in[3];
    float* out = (float*)d_out;

    const bool have_ws = ws_size >= (size_t)(1 + NV) * sizeof(int);
    if (have_ws) {
        int* wl = (int*)d_ws;
        hipMemsetAsync(wl, 0, sizeof(int), stream);   // reset worklist count
        geo_conv_f32<<<dim3(NV / VPB), dim3(256), 0, stream>>>(
            signal, bary_w, bary_idx, kern, out, wl);
        geo_refine_f64<<<dim3(128), dim3(256), 0, stream>>>(
            signal, bary_w, bary_idx, kern, out, wl, 0);
    } else {
        // fallback: full fp64 (round-2 behavior)
        geo_refine_f64<<<dim3(256), dim3(256), 0, stream>>>(
            signal, bary_w, bary_idx, kern, out, nullptr, NV);
    }
}